// Round 11
// baseline (211.980 us; speedup 1.0000x reference)
//
#include <hip/hip_runtime.h>
#include <hip/hip_bf16.h>

typedef __bf16 bf16;
typedef __bf16 bf16x8 __attribute__((ext_vector_type(8)));
typedef __bf16 bf16x4v __attribute__((ext_vector_type(4)));
typedef float  f32x4  __attribute__((ext_vector_type(4)));
typedef float  f32x16 __attribute__((ext_vector_type(16)));

#define SEQL  2048
#define BATCH 2
#define HID   2048
#define NH    16
#define NKVH  4
#define HD    128
#define NPROJ 3072
#define MROWS 4096   // SEQL*BATCH

// softmax scale folded into Q at qkv epilogue: scale * log2(e)
#define QSCALE (0.08838834764831845f * 1.44269504088896340f)

__device__ __forceinline__ void gload16(const void* src, void* dst) {
  __builtin_amdgcn_global_load_lds(
      (__attribute__((address_space(1))) void*)src,
      (__attribute__((address_space(3))) void*)dst, 16, 0, 0);
}

// XOR swizzles (involutions; applied identically on staging-source and ds_read)
__device__ __forceinline__ int swz128(int off) { return off ^ (((off >> 7) & 7) << 4); }  // 128B rows
__device__ __forceinline__ int swz256(int off) { return off ^ (((off >> 8) & 7) << 4); }  // 256B rows

__device__ __forceinline__ unsigned cvtpk_bf16(float lo, float hi) {
  unsigned r;
  asm("v_cvt_pk_bf16_f32 %0, %1, %2" : "=v"(r) : "v"(lo), "v"(hi));
  return r;
}
__device__ __forceinline__ void permswap32(unsigned& a, unsigned& b) {
  asm volatile("v_permlane32_swap_b32 %0, %1" : "+v"(a), "+v"(b));
}
__device__ __forceinline__ f32x16 mfma16(bf16x8 a, bf16x8 b, f32x16 c) {
  return __builtin_amdgcn_mfma_f32_32x32x16_bf16(a, b, c, 0, 0, 0);
}
__device__ __forceinline__ float sum16(const f32x16& v) {
  float a = (v[0] + v[1]) + (v[2] + v[3]);
  float b = (v[4] + v[5]) + (v[6] + v[7]);
  float c = (v[8] + v[9]) + (v[10] + v[11]);
  float d = (v[12] + v[13]) + (v[14] + v[15]);
  return (a + b) + (c + d);
}

// ---------------------------------------------------------------- convert
__global__ __launch_bounds__(256) void cvt_kernel(
    const float* __restrict__ x, const float* __restrict__ wq, const float* __restrict__ wp,
    bf16* __restrict__ xo, bf16* __restrict__ wqo, bf16* __restrict__ wpo) {
  const int NXQ  = (MROWS * HID) / 4;
  const int NWQQ = (NPROJ * HID) / 4;
  const int NWPQ = (HID * HID) / 4;
  const int total = NXQ + NWQQ + NWPQ;
  for (int i = blockIdx.x * blockDim.x + threadIdx.x; i < total; i += gridDim.x * blockDim.x) {
    const float4* src; bf16* dst; int j;
    if (i < NXQ)            { src = (const float4*)x;  dst = xo;  j = i; }
    else if (i < NXQ + NWQQ){ src = (const float4*)wq; dst = wqo; j = i - NXQ; }
    else                    { src = (const float4*)wp; dst = wpo; j = i - NXQ - NWQQ; }
    float4 v = src[j];
    bf16x4v o;
    o[0] = (bf16)v.x; o[1] = (bf16)v.y; o[2] = (bf16)v.z; o[3] = (bf16)v.w;
    *(bf16x4v*)(dst + (size_t)j * 4) = o;
  }
}

// ---------------------------------------------------------------- GEMM main loop (shared)
// BM=256, BK=64, 512 threads (8 waves = 2M x 4N), per-wave N = NF*16.
// Outer schedule = r10-validated counted-vmcnt (stage(t+2) after compute(t),
// vmcnt(4+NF) keeps t+2's loads in flight across barriers).
// NEW (r11): compute(t) is PHASE-SPLIT m201-style (race-free: no LDS writes
// during compute; only barriers + clustering added):
//   ph0: ds_read A-half0 + all B -> bar -> lgkmcnt(0) -> setprio{16 MFMA} -> bar
//   ph1: ds_read A-half1         -> bar -> lgkmcnt(0) -> setprio{MFMA}    -> bar
//   ph2: setprio{MFMA m4-7 x n-lo} -> bar
//   ph3: setprio{MFMA m4-7 x n-hi} -> bar (doubles as post-compute barrier)
// Phase-split creates wave role-diversity so T5 setprio pays (m218b: +21-25%
// on phase-split; null on coarse -- consistent with r9/r10's ~1065 TF/CU).
// Rule #18: sched_barrier(0) immediately after each inline lgkmcnt.
template<int NF, int BSZB>
__device__ __forceinline__ void gemm_main(
    const bf16* __restrict__ A, const bf16* __restrict__ Bm,
    int r0, int p0, char* lds, f32x4 (&acc)[8][NF], int tid, int l, int w) {
  const int wm = w >> 2, wn = w & 3;
  constexpr int NH0 = (NF + 1) / 2;   // n-lo count: NF=3 -> 2, NF=2 -> 1

  // staging source offsets (row + pre-swizzled chunk col)
  int sra[4], sca[4];
#pragma unroll
  for (int q = 0; q < 4; q++) {
    const int doff = (q * 512 + tid) * 16;
    sra[q] = doff >> 7;
    sca[q] = ((((doff >> 4) & 7) ^ (sra[q] & 7)) << 4);
  }
  int srb[NF], scb[NF];
#pragma unroll
  for (int q = 0; q < NF; q++) {
    const int doff = (q * 512 + tid) * 16;
    srb[q] = doff >> 7;
    scb[q] = ((((doff >> 4) & 7) ^ (srb[q] & 7)) << 4);
  }

  // fragment read offsets, fully swizzled per kk (r8 lesson: kk*64 is bit 6,
  // inside swz128's XOR mask -- does not commute)
  int aoff[8][2], boff[NF][2];
#pragma unroll
  for (int m = 0; m < 8; m++)
#pragma unroll
    for (int kk = 0; kk < 2; kk++)
      aoff[m][kk] = swz128((wm * 128 + m * 16 + (l & 15)) * 128 + kk * 64 + (l >> 4) * 16);
#pragma unroll
  for (int n = 0; n < NF; n++)
#pragma unroll
    for (int kk = 0; kk < 2; kk++)
      boff[n][kk] = swz128((wn * (NF * 16) + n * 16 + (l & 15)) * 128 + kk * 64 + (l >> 4) * 16);

  auto stage = [&](int t, int buf) {
    const int k0 = t * 64;
#pragma unroll
    for (int q = 0; q < 4; q++)
      gload16((const char*)A + ((size_t)(r0 + sra[q]) * HID + k0) * 2 + sca[q],
              lds + buf * 32768 + (q * 512 + w * 64) * 16);
#pragma unroll
    for (int q = 0; q < NF; q++)
      gload16((const char*)Bm + ((size_t)(p0 + srb[q]) * HID + k0) * 2 + scb[q],
              lds + 65536 + buf * BSZB + (q * 512 + w * 64) * 16);
  };

  auto compute = [&](int t) {
    const int ab = (t & 1) * 32768;
    const int bb = 65536 + (t & 1) * BSZB;
    bf16x8 a0[4][2], a1[4][2], bfv[NF][2];

    // ---- ph0: read A-half0 + all B; MFMA m0-3 x n[0,NH0)
#pragma unroll
    for (int m = 0; m < 4; m++)
#pragma unroll
      for (int kk = 0; kk < 2; kk++)
        a0[m][kk] = *(const bf16x8*)(lds + ab + aoff[m][kk]);
#pragma unroll
    for (int n = 0; n < NF; n++)
#pragma unroll
      for (int kk = 0; kk < 2; kk++)
        bfv[n][kk] = *(const bf16x8*)(lds + bb + boff[n][kk]);
    __builtin_amdgcn_sched_barrier(0);
    __builtin_amdgcn_s_barrier();
    asm volatile("s_waitcnt lgkmcnt(0)" ::: "memory");
    __builtin_amdgcn_sched_barrier(0);
    __builtin_amdgcn_s_setprio(1);
#pragma unroll
    for (int kk = 0; kk < 2; kk++)
#pragma unroll
      for (int m = 0; m < 4; m++)
#pragma unroll
        for (int n = 0; n < NH0; n++)
          acc[m][n] = __builtin_amdgcn_mfma_f32_16x16x32_bf16(a0[m][kk], bfv[n][kk], acc[m][n], 0, 0, 0);
    __builtin_amdgcn_s_setprio(0);
    __builtin_amdgcn_sched_barrier(0);
    __builtin_amdgcn_s_barrier();
    __builtin_amdgcn_sched_barrier(0);

    // ---- ph1: read A-half1; MFMA m0-3 x n[NH0,NF)
#pragma unroll
    for (int m = 0; m < 4; m++)
#pragma unroll
      for (int kk = 0; kk < 2; kk++)
        a1[m][kk] = *(const bf16x8*)(lds + ab + aoff[4 + m][kk]);
    __builtin_amdgcn_sched_barrier(0);
    __builtin_amdgcn_s_barrier();
    asm volatile("s_waitcnt lgkmcnt(0)" ::: "memory");
    __builtin_amdgcn_sched_barrier(0);
    __builtin_amdgcn_s_setprio(1);
#pragma unroll
    for (int kk = 0; kk < 2; kk++)
#pragma unroll
      for (int m = 0; m < 4; m++)
#pragma unroll
        for (int n = NH0; n < NF; n++)
          acc[m][n] = __builtin_amdgcn_mfma_f32_16x16x32_bf16(a0[m][kk], bfv[n][kk], acc[m][n], 0, 0, 0);
    __builtin_amdgcn_s_setprio(0);
    __builtin_amdgcn_sched_barrier(0);
    __builtin_amdgcn_s_barrier();
    __builtin_amdgcn_sched_barrier(0);

    // ---- ph2: MFMA m4-7 x n[0,NH0) (pure-reg cluster)
    __builtin_amdgcn_s_setprio(1);
#pragma unroll
    for (int kk = 0; kk < 2; kk++)
#pragma unroll
      for (int m = 0; m < 4; m++)
#pragma unroll
        for (int n = 0; n < NH0; n++)
          acc[4 + m][n] = __builtin_amdgcn_mfma_f32_16x16x32_bf16(a1[m][kk], bfv[n][kk], acc[4 + m][n], 0, 0, 0);
    __builtin_amdgcn_s_setprio(0);
    __builtin_amdgcn_sched_barrier(0);
    __builtin_amdgcn_s_barrier();
    __builtin_amdgcn_sched_barrier(0);

    // ---- ph3: MFMA m4-7 x n[NH0,NF); trailing barrier = post-compute barrier
    __builtin_amdgcn_s_setprio(1);
#pragma unroll
    for (int kk = 0; kk < 2; kk++)
#pragma unroll
      for (int m = 0; m < 4; m++)
#pragma unroll
        for (int n = NH0; n < NF; n++)
          acc[4 + m][n] = __builtin_amdgcn_mfma_f32_16x16x32_bf16(a1[m][kk], bfv[n][kk], acc[4 + m][n], 0, 0, 0);
    __builtin_amdgcn_s_setprio(0);
    __builtin_amdgcn_sched_barrier(0);
    __builtin_amdgcn_s_barrier();                    // all waves done reading buf[t&1]
    __builtin_amdgcn_sched_barrier(0);
  };

  stage(0, 0);
  stage(1, 1);
  if constexpr (NF == 3) asm volatile("s_waitcnt vmcnt(7)" ::: "memory");
  else                   asm volatile("s_waitcnt vmcnt(6)" ::: "memory");
  __builtin_amdgcn_sched_barrier(0);
  __builtin_amdgcn_s_barrier();
  __builtin_amdgcn_sched_barrier(0);

  const int NT = HID / 64;
  for (int t = 0; t < NT; ++t) {
    compute(t);                                      // ends with post-compute barrier
    if (t + 2 < NT) {
      stage(t + 2, t & 1);
      if constexpr (NF == 3) asm volatile("s_waitcnt vmcnt(7)" ::: "memory");
      else                   asm volatile("s_waitcnt vmcnt(6)" ::: "memory");
    } else if (t + 1 < NT) {
      asm volatile("s_waitcnt vmcnt(0)" ::: "memory");
    }
    __builtin_amdgcn_sched_barrier(0);
    __builtin_amdgcn_s_barrier();
    __builtin_amdgcn_sched_barrier(0);
  }
}

// ---------------------------------------------------------------- QKV GEMM
// 256x192 tile -> grid 16x16 = 256 blocks = 1/CU. LDS 112KB.
__global__ __launch_bounds__(512) void qkv_gemm(
    const bf16* __restrict__ A, const bf16* __restrict__ B,
    bf16* __restrict__ Qo, bf16* __restrict__ Ko, bf16* __restrict__ Vt) {
  __shared__ char lds[114688];  // A: 2x32KB @0 | B: 2x24KB @65536
  const int tid = threadIdx.x, l = tid & 63, w = tid >> 6;
  const int wm = w >> 2, wn = w & 3;
  // bijective XCD swizzle: 256 blocks = 8*32
  const int lin = blockIdx.x;
  const int swz = (lin & 7) * 32 + (lin >> 3);
  const int bx = swz & 15, by = swz >> 4;
  const int r0 = by * 256, p0 = bx * 192;

  f32x4 acc[8][3];
  const f32x4 fzero = {0.f, 0.f, 0.f, 0.f};
#pragma unroll
  for (int m = 0; m < 8; m++)
#pragma unroll
    for (int n = 0; n < 3; n++) acc[m][n] = fzero;

  gemm_main<3, 24576>(A, B, r0, p0, lds, acc, tid, l, w);

  // epilogue: seg logic per n-tile (16-col tiles never cross a 128 boundary)
#pragma unroll
  for (int m = 0; m < 8; m++) {
    const int rbase = r0 + wm * 128 + m * 16 + ((l >> 4) << 2);
#pragma unroll
    for (int n = 0; n < 3; n++) {
      const int pc = p0 + wn * 48 + n * 16;          // 16-aligned
      const int seg = (pc % 768) / 128;
      const int g = pc / 768;
      const int c = (pc % 128) + (l & 15);           // d within head
#pragma unroll
      for (int rg = 0; rg < 4; ++rg) {
        const int r = rbase + rg;
        const int s = r >> 1, b = r & 1;
        if (seg < 4) {
          const int h = g * 4 + seg;
          // pre-scale Q by softmax-scale*log2e (attn softmax in exp2 domain)
          Qo[(((size_t)(b * 16 + h)) * 2048 + s) * 128 + c] = (bf16)(acc[m][n][rg] * QSCALE);
        } else if (seg == 4) {
          Ko[(((size_t)(b * 4 + g)) * 2048 + s) * 128 + c] = (bf16)acc[m][n][rg];
        } else {
          Vt[(((size_t)(b * 4 + g)) * 128 + c) * 2048 + s] = (bf16)acc[m][n][rg];
        }
      }
    }
  }
}

// ---------------------------------------------------------------- proj GEMM
// 256x128 tile -> grid 16x16 = 256 blocks = 1/CU. LDS 96KB. Same schedule.
__global__ __launch_bounds__(512) void proj_gemm(
    const bf16* __restrict__ A, const bf16* __restrict__ B, float* __restrict__ C) {
  __shared__ char lds[98304];  // A: 2x32KB @0 | B: 2x16KB @65536
  const int tid = threadIdx.x, l = tid & 63, w = tid >> 6;
  const int wm = w >> 2, wn = w & 3;
  // bijective XCD swizzle: 256 blocks = 8*32
  const int lin = blockIdx.x;
  const int swz = (lin & 7) * 32 + (lin >> 3);
  const int bx = swz & 15, by = swz >> 4;
  const int r0 = by * 256, p0 = bx * 128;

  f32x4 acc[8][2];
  const f32x4 fzero = {0.f, 0.f, 0.f, 0.f};
#pragma unroll
  for (int m = 0; m < 8; m++)
#pragma unroll
    for (int n = 0; n < 2; n++) acc[m][n] = fzero;

  gemm_main<2, 16384>(A, B, r0, p0, lds, acc, tid, l, w);

#pragma unroll
  for (int m = 0; m < 8; m++) {
    const int rbase = r0 + wm * 128 + m * 16 + ((l >> 4) << 2);
#pragma unroll
    for (int n = 0; n < 2; n++) {
      const int c = p0 + wn * 32 + n * 16 + (l & 15);
#pragma unroll
      for (int rg = 0; rg < 4; ++rg)
        C[(size_t)(rbase + rg) * HID + c] = acc[m][n][rg];
    }
  }
}

// ---------------------------------------------------------------- attention
// r9/r10 kernel unchanged (91.0-91.3 us measured): q=32/wave, 512 blocks,
// 2 blocks/CU, K+V LDS dbuf, static-max softmax, SM/PV interleave, VALU l-sum.
template<int BASE>
__device__ __forceinline__ void attn_tile(
    char* lds, const bf16x8* qf, const int* ka, const int* va,
    f32x16* oacc, float& lp) {
  const f32x16 z16 = {};

  // S^T = mfma(K, Q): lane holds col q=l31; rows t = (reg&3)+8*(reg>>2)+4*h2 (+32*tsub)
  f32x16 sT0 = z16, sT1 = z16;
  __builtin_amdgcn_s_setprio(1);
#pragma unroll
  for (int s = 0; s < 8; s++) {
    bf16x8 kf = *(const bf16x8*)(lds + BASE + ka[s]);
    sT0 = mfma16(kf, qf[s], sT0);
  }
#pragma unroll
  for (int s = 0; s < 8; s++) {
    bf16x8 kf = *(const bf16x8*)(lds + BASE + ka[8 + s]);
    sT1 = mfma16(kf, qf[s], sT1);
  }
  __builtin_amdgcn_s_setprio(0);

  // SM0: P0 = exp2(S0) (static-max; normalized by l at epilogue), pack c0.
  unsigned c0[8], c1[8];
#pragma unroll
  for (int i = 0; i < 16; i++) sT0[i] = exp2f(sT0[i]);
  lp += sum16(sT0);
#pragma unroll
  for (int i = 0; i < 8; i++) c0[i] = cvtpk_bf16(sT0[2 * i], sT0[2 * i + 1]);
  permswap32(c0[0], c0[2]); permswap32(c0[1], c0[3]);
  permswap32(c0[4], c0[6]); permswap32(c0[5], c0[7]);

  // PV ks=0,1 (consumes c0 only) -- issued before SM1's VALU work
  __builtin_amdgcn_s_setprio(1);
#pragma unroll
  for (int ks = 0; ks < 2; ks++) {
    union { unsigned u[4]; bf16x8 v; } pb;
#pragma unroll
    for (int i = 0; i < 4; i++) pb.u[i] = c0[(ks & 1) * 4 + i];
#pragma unroll
    for (int dblk = 0; dblk < 4; dblk++) {
      bf16x8 vf = *(const bf16x8*)(lds + BASE + 16384 + va[ks * 4 + dblk]);
      oacc[dblk] = mfma16(vf, pb.v, oacc[dblk]);
    }
  }
  __builtin_amdgcn_s_setprio(0);

  // SM1 on the VALU while PV ks01 MFMAs drain
#pragma unroll
  for (int i = 0; i < 16; i++) sT1[i] = exp2f(sT1[i]);
  lp += sum16(sT1);
#pragma unroll
  for (int i = 0; i < 8; i++) c1[i] = cvtpk_bf16(sT1[2 * i], sT1[2 * i + 1]);
  permswap32(c1[0], c1[2]); permswap32(c1[1], c1[3]);
  permswap32(c1[4], c1[6]); permswap32(c1[5], c1[7]);

  // PV ks=2,3 (consumes c1)
  __builtin_amdgcn_s_setprio(1);
#pragma unroll
  for (int ks = 2; ks < 4; ks++) {
    union { unsigned u[4]; bf16x8 v; } pb;
#pragma unroll
    for (int i = 0; i < 4; i++) pb.u[i] = c1[(ks & 1) * 4 + i];
#pragma unroll
    for (int dblk = 0; dblk < 4; dblk++) {
      bf16x8 vf = *(const bf16x8*)(lds + BASE + 16384 + va[ks * 4 + dblk]);
      oacc[dblk] = mfma16(vf, pb.v, oacc[dblk]);
    }
  }
  __builtin_amdgcn_s_setprio(0);
}

__global__ __launch_bounds__(256, 2) void attn_kernel(
    const bf16* __restrict__ Q, const bf16* __restrict__ K, const bf16* __restrict__ V,
    bf16* __restrict__ O) {
  __shared__ char lds[65536];  // 2 x { K:[64][128] 16KB, V^T:[128][64] 16KB }
  const int tid = threadIdx.x, l = tid & 63, w = tid >> 6;
  const int l31 = l & 31, h2 = l >> 5;
  // XCD-aware swizzle (T1): 512 blocks = 8*64
  const int lin = blockIdx.x + (blockIdx.y << 4);
  const int swzb = (lin & 7) * 64 + (lin >> 3);
  const int qt = swzb & 15, bh = swzb >> 4;
  const int b = bh >> 4, head = bh & 15, g = head >> 2;

  const int q0 = qt * 128 + w * 32;

  // Q as MFMA B-operand: lane holds col q = l31, k-elems d = 16s + 8*h2 + j
  bf16x8 qf[8];
  {
    const bf16* qbase = Q + (((size_t)(b * 16 + head)) * 2048 + q0 + l31) * 128 + h2 * 8;
#pragma unroll
    for (int s = 0; s < 8; s++) qf[s] = *(const bf16x8*)(qbase + s * 16);
  }

  // hoisted per-lane ds_read offsets (loop-invariant)
  int ka[16], va[16];
#pragma unroll
  for (int tsub = 0; tsub < 2; tsub++)
#pragma unroll
    for (int s = 0; s < 8; s++)
      ka[tsub * 8 + s] = swz256((tsub * 32 + l31) * 256 + s * 32 + h2 * 16);
#pragma unroll
  for (int ks = 0; ks < 4; ks++)
#pragma unroll
    for (int dblk = 0; dblk < 4; dblk++)
      va[ks * 4 + dblk] = swz128((dblk * 32 + l31) * 128 + ks * 32 + h2 * 16);

  // hoisted staging source offsets
  int kso[4], vso[4];
#pragma unroll
  for (int q = 0; q < 4; q++) {
    const int off = (q * 4 + w) * 1024 + l * 16;
    kso[q] = swz256(off);
    const int rowv = off >> 7;
    const int chv = ((off >> 4) & 7) ^ (rowv & 7);
    vso[q] = rowv * 4096 + chv * 16;  // bytes: (rowv*2048)*2 + chv*16
  }

  const f32x16 z16 = {};
  f32x16 oacc[4];
#pragma unroll
  for (int d = 0; d < 4; d++) oacc[d] = z16;
  float lp = 0.f;

  const char* kbase = (const char*)(K + ((size_t)(b * 4 + g)) * 2048 * 128);
  const char* vbase = (const char*)(V + ((size_t)(b * 4 + g)) * 128 * 2048);

  // stage(tile t, buffer base B)
  auto stage = [&](int t0, int B) {
#pragma unroll
    for (int q = 0; q < 4; q++) {
      gload16(kbase + (size_t)t0 * 256 + kso[q], lds + B + (q * 4 + w) * 1024);
      gload16(vbase + (size_t)t0 * 2 + vso[q], lds + B + 16384 + (q * 4 + w) * 1024);
    }
  };

  stage(0, 0);
  __syncthreads();

  for (int t0 = 0; t0 < SEQL; t0 += 128) {
    stage(t0 + 64, 32768);
    attn_tile<0>(lds, qf, ka, va, oacc, lp);
    __syncthreads();
    if (t0 + 128 < SEQL) stage(t0 + 128, 0);
    attn_tile<32768>(lds, qf, ka, va, oacc, lp);
    __syncthreads();
  }

  // epilogue: lane owns q = q0+l31; O^T reg r of oacc[dblk] is d = 32*dblk + 8*(r>>2) + 4*h2 + (r&3)
  // l(q) = lp(h2) + lp(h2^1): the two h2 halves partition the kv rows.
  const float inv = 1.0f / (lp + __shfl_xor(lp, 32));
  const size_t rowo = ((size_t)(q0 + l31) * 2 + b) * 2048 + (size_t)head * 128;
#pragma unroll
  for (int dblk = 0; dblk < 4; dblk++)
#pragma unroll
    for (int g4 = 0; g4 < 4; g4++) {
      bf16x4v ov;
#pragma unroll
      for (int e = 0; e < 4; e++) ov[e] = (bf16)(oacc[dblk][g4 * 4 + e] * inv);
      *(bf16x4v*)(O + rowo + dblk * 32 + g4 * 8 + h2 * 4) = ov;
    }
}

// ---------------------------------------------------------------- launch
extern "C" void kernel_launch(void* const* d_in, const int* in_sizes, int n_in,
                              void* d_out, int out_size, void* d_ws, size_t ws_size,
                              hipStream_t stream) {
  const float* x  = (const float*)d_in[0];
  const float* wq = (const float*)d_in[1];
  const float* wp = (const float*)d_in[2];
  float* out = (float*)d_out;
  char* ws = (char*)d_ws;

  size_t off = 0;
  bf16* xb  = (bf16*)(ws + off); off += (size_t)MROWS * HID * 2;   // 16 MB (reused as O later)
  bf16* wqb = (bf16*)(ws + off); off += (size_t)NPROJ * HID * 2;   // 12 MB
  bf16* wpb = (bf16*)(ws + off); off += (size_t)HID * HID * 2;     //  8 MB
  bf16* Qb  = (bf16*)(ws + off); off += (size_t)2 * 16 * 2048 * 128 * 2;  // 16 MB
  bf16* Kb  = (bf16*)(ws + off); off += (size_t)2 * 4 * 2048 * 128 * 2;   //  4 MB
  bf16* Vb  = (bf16*)(ws + off); off += (size_t)2 * 4 * 128 * 2048 * 2;   //  4 MB
  bf16* Ob  = xb;  // x_bf16 is dead after qkv_gemm; alias O onto it

  cvt_kernel<<<2048, 256, 0, stream>>>(x, wq, wp, xb, wqb, wpb);
  qkv_gemm<<<dim3(256), 512, 0, stream>>>(xb, wqb, Qb, Kb, Vb);
  attn_kernel<<<dim3(16, 32), 256, 0, stream>>>(Qb, Kb, Vb, Ob);
  proj_gemm<<<dim3(256), 512, 0, stream>>>(Ob, wpb, out);
}

// Round 12
// 201.433 us; speedup vs baseline: 1.0524x; 1.0524x over previous
//
#include <hip/hip_runtime.h>
#include <hip/hip_bf16.h>

typedef __bf16 bf16;
typedef __bf16 bf16x8 __attribute__((ext_vector_type(8)));
typedef __bf16 bf16x4v __attribute__((ext_vector_type(4)));
typedef float  f32x4  __attribute__((ext_vector_type(4)));
typedef float  f32x16 __attribute__((ext_vector_type(16)));

#define SEQL  2048
#define BATCH 2
#define HID   2048
#define NH    16
#define NKVH  4
#define HD    128
#define NPROJ 3072
#define MROWS 4096   // SEQL*BATCH

// softmax scale folded into Q at qkv epilogue: scale * log2(e)
#define QSCALE (0.08838834764831845f * 1.44269504088896340f)

__device__ __forceinline__ void gload16(const void* src, void* dst) {
  __builtin_amdgcn_global_load_lds(
      (__attribute__((address_space(1))) void*)src,
      (__attribute__((address_space(3))) void*)dst, 16, 0, 0);
}

// XOR swizzles (involutions; applied identically on staging-source and ds_read)
__device__ __forceinline__ int swz128(int off) { return off ^ (((off >> 7) & 7) << 4); }  // 128B rows
__device__ __forceinline__ int swz256(int off) { return off ^ (((off >> 8) & 7) << 4); }  // 256B rows

__device__ __forceinline__ unsigned cvtpk_bf16(float lo, float hi) {
  unsigned r;
  asm("v_cvt_pk_bf16_f32 %0, %1, %2" : "=v"(r) : "v"(lo), "v"(hi));
  return r;
}
__device__ __forceinline__ void permswap32(unsigned& a, unsigned& b) {
  asm volatile("v_permlane32_swap_b32 %0, %1" : "+v"(a), "+v"(b));
}
__device__ __forceinline__ f32x16 mfma16(bf16x8 a, bf16x8 b, f32x16 c) {
  return __builtin_amdgcn_mfma_f32_32x32x16_bf16(a, b, c, 0, 0, 0);
}
__device__ __forceinline__ float sum16(const f32x16& v) {
  float a = (v[0] + v[1]) + (v[2] + v[3]);
  float b = (v[4] + v[5]) + (v[6] + v[7]);
  float c = (v[8] + v[9]) + (v[10] + v[11]);
  float d = (v[12] + v[13]) + (v[14] + v[15]);
  return (a + b) + (c + d);
}

// ---------------------------------------------------------------- convert (x, w_qkv; w_proj fused into qkv epilogue)
__global__ __launch_bounds__(256) void cvt_kernel(
    const float* __restrict__ x, const float* __restrict__ wq,
    bf16* __restrict__ xo, bf16* __restrict__ wqo) {
  const int NXQ  = (MROWS * HID) / 4;
  const int NWQQ = (NPROJ * HID) / 4;
  const int total = NXQ + NWQQ;
  for (int i = blockIdx.x * blockDim.x + threadIdx.x; i < total; i += gridDim.x * blockDim.x) {
    const float4* src; bf16* dst; int j;
    if (i < NXQ) { src = (const float4*)x;  dst = xo;  j = i; }
    else         { src = (const float4*)wq; dst = wqo; j = i - NXQ; }
    float4 v = src[j];
    bf16x4v o;
    o[0] = (bf16)v.x; o[1] = (bf16)v.y; o[2] = (bf16)v.z; o[3] = (bf16)v.w;
    *(bf16x4v*)(dst + (size_t)j * 4) = o;
  }
}

// ---------------------------------------------------------------- QKV GEMM
// 128x128 tile (longest-validated form, ~905 TF/CU) + w_proj f32->bf16
// conversion fused AFTER the epilogue: qkv's HBM pipe is ~2% busy, 3
// blocks/CU of TLP hide the burst, acc regs are dead by then, and wpb is
// consumed two kernel-boundaries later (proj) -> ordering guaranteed.
// (r7 lesson: the same fuse in attn's PROLOGUE cost +5us -- placement at a
// kernel START delays pipeline fill; placement at END overlaps stragglers.)
__global__ __launch_bounds__(256, 3) void qkv_gemm(
    const bf16* __restrict__ A, const bf16* __restrict__ B,
    bf16* __restrict__ Qo, bf16* __restrict__ Ko, bf16* __restrict__ Vt,
    const float* __restrict__ wp, bf16* __restrict__ wpb) {
  __shared__ char lds[32768];
  const int tid = threadIdx.x, l = tid & 63, w = tid >> 6;
  // XCD-aware swizzle (T1): grid 24x32 = 768 = 8*96
  const int lin = blockIdx.x + 24 * blockIdx.y;
  const int swz = (lin & 7) * 96 + (lin >> 3);
  const int bx = swz % 24, by = swz / 24;
  const int r0 = by * 128, p0 = bx * 128;
  const int wr = w >> 1, wc = w & 1;

  f32x4 acc[4][4];
  const f32x4 fzero = {0.f, 0.f, 0.f, 0.f};
#pragma unroll
  for (int m = 0; m < 4; m++)
#pragma unroll
    for (int n = 0; n < 4; n++) acc[m][n] = fzero;

  for (int kt = 0; kt < HID / 64; ++kt) {
    const int k0 = kt * 64;
    __syncthreads();
#pragma unroll
    for (int q = 0; q < 4; q++) {
      const int doff = (w * 4 + q) * 1024 + l * 16;
      const int row = doff >> 7;
      const int chv = ((doff >> 4) & 7) ^ (row & 7);
      gload16((const char*)A + ((size_t)(r0 + row) * HID + k0) * 2 + chv * 16,
              lds + (w * 4 + q) * 1024);
      gload16((const char*)B + ((size_t)(p0 + row) * HID + k0) * 2 + chv * 16,
              lds + 16384 + (w * 4 + q) * 1024);
    }
    __syncthreads();
    bf16x8 af[4][2], bfr[4][2];
#pragma unroll
    for (int m = 0; m < 4; m++)
#pragma unroll
      for (int kk = 0; kk < 2; kk++) {
        int off = (wr * 64 + m * 16 + (l & 15)) * 128 + kk * 64 + (l >> 4) * 16;
        af[m][kk] = *(const bf16x8*)(lds + swz128(off));
      }
#pragma unroll
    for (int n = 0; n < 4; n++)
#pragma unroll
      for (int kk = 0; kk < 2; kk++) {
        int off = (wc * 64 + n * 16 + (l & 15)) * 128 + kk * 64 + (l >> 4) * 16;
        bfr[n][kk] = *(const bf16x8*)(lds + 16384 + swz128(off));
      }
#pragma unroll
    for (int kk = 0; kk < 2; kk++)
#pragma unroll
      for (int m = 0; m < 4; m++)
#pragma unroll
        for (int n = 0; n < 4; n++)
          acc[m][n] = __builtin_amdgcn_mfma_f32_16x16x32_bf16(af[m][kk], bfr[n][kk], acc[m][n], 0, 0, 0);
  }

  const int seg = (p0 % 768) / 128;
  const int g = p0 / 768;
#pragma unroll
  for (int m = 0; m < 4; m++) {
    const int rbase = r0 + wr * 64 + m * 16 + ((l >> 4) << 2);
#pragma unroll
    for (int n = 0; n < 4; n++) {
      const int c = wc * 64 + n * 16 + (l & 15);  // d within head
#pragma unroll
      for (int rg = 0; rg < 4; ++rg) {
        const int r = rbase + rg;
        const int s = r >> 1, b = r & 1;
        if (seg < 4) {
          const int h = g * 4 + seg;
          // pre-scale Q by softmax-scale*log2e so attn softmax works in exp2 domain
          Qo[(((size_t)(b * 16 + h)) * 2048 + s) * 128 + c] = (bf16)(acc[m][n][rg] * QSCALE);
        } else if (seg == 4) {
          Ko[(((size_t)(b * 4 + g)) * 2048 + s) * 128 + c] = (bf16)acc[m][n][rg];
        } else {
          Vt[(((size_t)(b * 4 + g)) * 128 + c) * 2048 + s] = (bf16)acc[m][n][rg];
        }
      }
    }
  }

  // ---- fused w_proj f32->bf16 conversion (rides qkv's idle HBM pipe) ----
  {
    const int NWPQ = (HID * HID) / 4;                 // 1048576 float4s
    const int nthreads = 768 * 256;                   // grid * block
    for (int i = lin * 256 + tid; i < NWPQ; i += nthreads) {
      float4 v = ((const float4*)wp)[i];
      bf16x4v o;
      o[0] = (bf16)v.x; o[1] = (bf16)v.y; o[2] = (bf16)v.z; o[3] = (bf16)v.w;
      *(bf16x4v*)(wpb + (size_t)i * 4) = o;
    }
  }
}

// ---------------------------------------------------------------- attention
// r9/r10 kernel unchanged (91.0-91.3 us measured, best): q=32/wave, 512
// blocks, 2 blocks/CU, K+V LDS dbuf, static-max softmax (P = exp2(S),
// normalize by l at epilogue), SM/PV interleave, VALU l-sum.
template<int BASE>
__device__ __forceinline__ void attn_tile(
    char* lds, const bf16x8* qf, const int* ka, const int* va,
    f32x16* oacc, float& lp) {
  const f32x16 z16 = {};

  // S^T = mfma(K, Q): lane holds col q=l31; rows t = (reg&3)+8*(reg>>2)+4*h2 (+32*tsub)
  f32x16 sT0 = z16, sT1 = z16;
  __builtin_amdgcn_s_setprio(1);
#pragma unroll
  for (int s = 0; s < 8; s++) {
    bf16x8 kf = *(const bf16x8*)(lds + BASE + ka[s]);
    sT0 = mfma16(kf, qf[s], sT0);
  }
#pragma unroll
  for (int s = 0; s < 8; s++) {
    bf16x8 kf = *(const bf16x8*)(lds + BASE + ka[8 + s]);
    sT1 = mfma16(kf, qf[s], sT1);
  }
  __builtin_amdgcn_s_setprio(0);

  // SM0: P0 = exp2(S0) (static-max; normalized by l at epilogue), pack c0.
  unsigned c0[8], c1[8];
#pragma unroll
  for (int i = 0; i < 16; i++) sT0[i] = exp2f(sT0[i]);
  lp += sum16(sT0);
#pragma unroll
  for (int i = 0; i < 8; i++) c0[i] = cvtpk_bf16(sT0[2 * i], sT0[2 * i + 1]);
  permswap32(c0[0], c0[2]); permswap32(c0[1], c0[3]);
  permswap32(c0[4], c0[6]); permswap32(c0[5], c0[7]);

  // PV ks=0,1 (consumes c0 only) -- issued before SM1's VALU work
  __builtin_amdgcn_s_setprio(1);
#pragma unroll
  for (int ks = 0; ks < 2; ks++) {
    union { unsigned u[4]; bf16x8 v; } pb;
#pragma unroll
    for (int i = 0; i < 4; i++) pb.u[i] = c0[(ks & 1) * 4 + i];
#pragma unroll
    for (int dblk = 0; dblk < 4; dblk++) {
      bf16x8 vf = *(const bf16x8*)(lds + BASE + 16384 + va[ks * 4 + dblk]);
      oacc[dblk] = mfma16(vf, pb.v, oacc[dblk]);
    }
  }
  __builtin_amdgcn_s_setprio(0);

  // SM1 on the VALU while PV ks01 MFMAs drain
#pragma unroll
  for (int i = 0; i < 16; i++) sT1[i] = exp2f(sT1[i]);
  lp += sum16(sT1);
#pragma unroll
  for (int i = 0; i < 8; i++) c1[i] = cvtpk_bf16(sT1[2 * i], sT1[2 * i + 1]);
  permswap32(c1[0], c1[2]); permswap32(c1[1], c1[3]);
  permswap32(c1[4], c1[6]); permswap32(c1[5], c1[7]);

  // PV ks=2,3 (consumes c1)
  __builtin_amdgcn_s_setprio(1);
#pragma unroll
  for (int ks = 2; ks < 4; ks++) {
    union { unsigned u[4]; bf16x8 v; } pb;
#pragma unroll
    for (int i = 0; i < 4; i++) pb.u[i] = c1[(ks & 1) * 4 + i];
#pragma unroll
    for (int dblk = 0; dblk < 4; dblk++) {
      bf16x8 vf = *(const bf16x8*)(lds + BASE + 16384 + va[ks * 4 + dblk]);
      oacc[dblk] = mfma16(vf, pb.v, oacc[dblk]);
    }
  }
  __builtin_amdgcn_s_setprio(0);
}

__global__ __launch_bounds__(256, 2) void attn_kernel(
    const bf16* __restrict__ Q, const bf16* __restrict__ K, const bf16* __restrict__ V,
    bf16* __restrict__ O) {
  __shared__ char lds[65536];  // 2 x { K:[64][128] 16KB, V^T:[128][64] 16KB }
  const int tid = threadIdx.x, l = tid & 63, w = tid >> 6;
  const int l31 = l & 31, h2 = l >> 5;
  // XCD-aware swizzle (T1): 512 blocks = 8*64
  const int lin = blockIdx.x + (blockIdx.y << 4);
  const int swzb = (lin & 7) * 64 + (lin >> 3);
  const int qt = swzb & 15, bh = swzb >> 4;
  const int b = bh >> 4, head = bh & 15, g = head >> 2;

  const int q0 = qt * 128 + w * 32;

  // Q as MFMA B-operand: lane holds col q = l31, k-elems d = 16s + 8*h2 + j
  bf16x8 qf[8];
  {
    const bf16* qbase = Q + (((size_t)(b * 16 + head)) * 2048 + q0 + l31) * 128 + h2 * 8;
#pragma unroll
    for (int s = 0; s < 8; s++) qf[s] = *(const bf16x8*)(qbase + s * 16);
  }

  // hoisted per-lane ds_read offsets (loop-invariant)
  int ka[16], va[16];
#pragma unroll
  for (int tsub = 0; tsub < 2; tsub++)
#pragma unroll
    for (int s = 0; s < 8; s++)
      ka[tsub * 8 + s] = swz256((tsub * 32 + l31) * 256 + s * 32 + h2 * 16);
#pragma unroll
  for (int ks = 0; ks < 4; ks++)
#pragma unroll
    for (int dblk = 0; dblk < 4; dblk++)
      va[ks * 4 + dblk] = swz128((dblk * 32 + l31) * 128 + ks * 32 + h2 * 16);

  // hoisted staging source offsets
  int kso[4], vso[4];
#pragma unroll
  for (int q = 0; q < 4; q++) {
    const int off = (q * 4 + w) * 1024 + l * 16;
    kso[q] = swz256(off);
    const int rowv = off >> 7;
    const int chv = ((off >> 4) & 7) ^ (rowv & 7);
    vso[q] = rowv * 4096 + chv * 16;  // bytes: (rowv*2048)*2 + chv*16
  }

  const f32x16 z16 = {};
  f32x16 oacc[4];
#pragma unroll
  for (int d = 0; d < 4; d++) oacc[d] = z16;
  float lp = 0.f;

  const char* kbase = (const char*)(K + ((size_t)(b * 4 + g)) * 2048 * 128);
  const char* vbase = (const char*)(V + ((size_t)(b * 4 + g)) * 128 * 2048);

  // stage(tile t, buffer base B)
  auto stage = [&](int t0, int B) {
#pragma unroll
    for (int q = 0; q < 4; q++) {
      gload16(kbase + (size_t)t0 * 256 + kso[q], lds + B + (q * 4 + w) * 1024);
      gload16(vbase + (size_t)t0 * 2 + vso[q], lds + B + 16384 + (q * 4 + w) * 1024);
    }
  };

  stage(0, 0);
  __syncthreads();

  for (int t0 = 0; t0 < SEQL; t0 += 128) {
    stage(t0 + 64, 32768);
    attn_tile<0>(lds, qf, ka, va, oacc, lp);
    __syncthreads();
    if (t0 + 128 < SEQL) stage(t0 + 128, 0);
    attn_tile<32768>(lds, qf, ka, va, oacc, lp);
    __syncthreads();
  }

  // epilogue: lane owns q = q0+l31; O^T reg r of oacc[dblk] is d = 32*dblk + 8*(r>>2) + 4*h2 + (r&3)
  // l(q) = lp(h2) + lp(h2^1): the two h2 halves partition the kv rows.
  const float inv = 1.0f / (lp + __shfl_xor(lp, 32));
  const size_t rowo = ((size_t)(q0 + l31) * 2 + b) * 2048 + (size_t)head * 128;
#pragma unroll
  for (int dblk = 0; dblk < 4; dblk++)
#pragma unroll
    for (int g4 = 0; g4 < 4; g4++) {
      bf16x4v ov;
#pragma unroll
      for (int e = 0; e < 4; e++) ov[e] = (bf16)(oacc[dblk][g4 * 4 + e] * inv);
      *(bf16x4v*)(O + rowo + dblk * 32 + g4 * 8 + h2 * 4) = ov;
    }
}

// ---------------------------------------------------------------- proj GEMM
// 128x128 tile (validated form, ~905 TF/CU).
__global__ __launch_bounds__(256, 2) void proj_gemm(
    const bf16* __restrict__ A, const bf16* __restrict__ B, float* __restrict__ C) {
  __shared__ char lds[32768];
  const int tid = threadIdx.x, l = tid & 63, w = tid >> 6;
  // XCD-aware swizzle (T1): 512 blocks = 8*64
  const int lin = blockIdx.x + (blockIdx.y << 4);
  const int swz = (lin & 7) * 64 + (lin >> 3);
  const int bx = swz & 15, by = swz >> 4;
  const int r0 = by * 128, p0 = bx * 128;
  const int wr = w >> 1, wc = w & 1;

  f32x4 acc[4][4];
  const f32x4 fzero = {0.f, 0.f, 0.f, 0.f};
#pragma unroll
  for (int m = 0; m < 4; m++)
#pragma unroll
    for (int n = 0; n < 4; n++) acc[m][n] = fzero;

  for (int kt = 0; kt < HID / 64; ++kt) {
    const int k0 = kt * 64;
    __syncthreads();
#pragma unroll
    for (int q = 0; q < 4; q++) {
      const int doff = (w * 4 + q) * 1024 + l * 16;
      const int row = doff >> 7;
      const int chv = ((doff >> 4) & 7) ^ (row & 7);
      gload16((const char*)A + ((size_t)(r0 + row) * HID + k0) * 2 + chv * 16,
              lds + (w * 4 + q) * 1024);
      gload16((const char*)B + ((size_t)(p0 + row) * HID + k0) * 2 + chv * 16,
              lds + 16384 + (w * 4 + q) * 1024);
    }
    __syncthreads();
    bf16x8 af[4][2], bfr[4][2];
#pragma unroll
    for (int m = 0; m < 4; m++)
#pragma unroll
      for (int kk = 0; kk < 2; kk++) {
        int off = (wr * 64 + m * 16 + (l & 15)) * 128 + kk * 64 + (l >> 4) * 16;
        af[m][kk] = *(const bf16x8*)(lds + swz128(off));
      }
#pragma unroll
    for (int n = 0; n < 4; n++)
#pragma unroll
      for (int kk = 0; kk < 2; kk++) {
        int off = (wc * 64 + n * 16 + (l & 15)) * 128 + kk * 64 + (l >> 4) * 16;
        bfr[n][kk] = *(const bf16x8*)(lds + 16384 + swz128(off));
      }
#pragma unroll
    for (int kk = 0; kk < 2; kk++)
#pragma unroll
      for (int m = 0; m < 4; m++)
#pragma unroll
        for (int n = 0; n < 4; n++)
          acc[m][n] = __builtin_amdgcn_mfma_f32_16x16x32_bf16(af[m][kk], bfr[n][kk], acc[m][n], 0, 0, 0);
  }
#pragma unroll
  for (int m = 0; m < 4; m++) {
    const int rbase = r0 + wr * 64 + m * 16 + ((l >> 4) << 2);
#pragma unroll
    for (int n = 0; n < 4; n++) {
      const int c = p0 + wc * 64 + n * 16 + (l & 15);
#pragma unroll
      for (int rg = 0; rg < 4; ++rg)
        C[(size_t)(rbase + rg) * HID + c] = acc[m][n][rg];
    }
  }
}

// ---------------------------------------------------------------- launch
extern "C" void kernel_launch(void* const* d_in, const int* in_sizes, int n_in,
                              void* d_out, int out_size, void* d_ws, size_t ws_size,
                              hipStream_t stream) {
  const float* x  = (const float*)d_in[0];
  const float* wq = (const float*)d_in[1];
  const float* wp = (const float*)d_in[2];
  float* out = (float*)d_out;
  char* ws = (char*)d_ws;

  size_t off = 0;
  bf16* xb  = (bf16*)(ws + off); off += (size_t)MROWS * HID * 2;   // 16 MB (reused as O later)
  bf16* wqb = (bf16*)(ws + off); off += (size_t)NPROJ * HID * 2;   // 12 MB
  bf16* wpb = (bf16*)(ws + off); off += (size_t)HID * HID * 2;     //  8 MB
  bf16* Qb  = (bf16*)(ws + off); off += (size_t)2 * 16 * 2048 * 128 * 2;  // 16 MB
  bf16* Kb  = (bf16*)(ws + off); off += (size_t)2 * 4 * 2048 * 128 * 2;   //  4 MB
  bf16* Vb  = (bf16*)(ws + off); off += (size_t)2 * 4 * 128 * 2048 * 2;   //  4 MB
  bf16* Ob  = xb;  // x_bf16 is dead after qkv_gemm; alias O onto it

  cvt_kernel<<<2048, 256, 0, stream>>>(x, wq, xb, wqb);
  qkv_gemm<<<dim3(24, 32), 256, 0, stream>>>(xb, wqb, Qb, Kb, Vb, wp, wpb);
  attn_kernel<<<dim3(16, 32), 256, 0, stream>>>(Qb, Kb, Vb, Ob);
  proj_gemm<<<dim3(16, 32), 256, 0, stream>>>(Ob, wpb, out);
}